// Round 7
// baseline (35.923 us; speedup 1.0000x reference)
//
#include <hip/hip_runtime.h>
#include <math.h>

#define HID 2048
#define EMB 512
#define NV 16

__device__ __forceinline__ float dot4(float4 a, float4 b) {
    return a.x * b.x + a.y * b.y + a.z * b.z + a.w * b.w;
}

__device__ __forceinline__ float wred(float v) {
#pragma unroll
    for (int o = 32; o >= 1; o >>= 1) v += __shfl_down(v, o, 64);
    return v;
}

__device__ __forceinline__ float sig(float x) { return 1.0f / (1.0f + __expf(-x)); }

// k1: one WAVE per output row; no __syncthreads, no LDS. 4 rows per 256-thread block.
// blocks 0..511   -> h0 rows  j = bid*4 + wave
// blocks 512..1023 -> gh1 rows j = (bid-512)*4 + wave
__global__ __launch_bounds__(256, 4) void k1(
    const int* __restrict__ xidx,
    const float* __restrict__ h_in,
    const float* __restrict__ emb,
    const float* __restrict__ w_ih0,
    const float* __restrict__ w_hh0,
    const float* __restrict__ b_ih0,
    const float* __restrict__ b_hh0,
    const float* __restrict__ w_hh1,
    const float* __restrict__ b_hh1,
    float* __restrict__ out,
    float* __restrict__ gh1)
{
    const int tid = threadIdx.x;
    const int t   = tid & 63;    // lane within wave
    const int wv  = tid >> 6;    // wave 0..3
    const int bid = blockIdx.x;

    if (bid < 512) {
        const int j = bid * 4 + wv;
        // uniform prefetches for epilogue
        const float bi_r = b_ih0[j];
        const float bi_z = b_ih0[j + HID];
        const float bi_n = b_ih0[j + 2 * HID];
        const float bh_r = b_hh0[j];
        const float bh_z = b_hh0[j + HID];
        const float bh_n = b_hh0[j + 2 * HID];
        const float hprev = h_in[j];

        const float4* hv = (const float4*)h_in;                       // h_in[0], 512 float4
        const float4* wr = (const float4*)(w_hh0 + (size_t)j * HID);
        const float4* wz = (const float4*)(w_hh0 + (size_t)(j + HID) * HID);
        const float4* wn = (const float4*)(w_hh0 + (size_t)(j + 2 * HID) * HID);
        const float4* ev = (const float4*)(emb + (size_t)xidx[0] * EMB);
        const float4* pr = (const float4*)(w_ih0 + (size_t)j * EMB);
        const float4* pz = (const float4*)(w_ih0 + (size_t)(j + HID) * EMB);
        const float4* pn = (const float4*)(w_ih0 + (size_t)(j + 2 * HID) * EMB);

        // x vector: 8 float4/lane (L2-resident after first blocks)
        float4 x0 = hv[t],       x1 = hv[t + 64],  x2 = hv[t + 128], x3 = hv[t + 192];
        float4 x4 = hv[t + 256], x5 = hv[t + 320], x6 = hv[t + 384], x7 = hv[t + 448];

        // weight half 1: 12 independent loads in flight
        float4 a0 = wr[t], a1 = wr[t + 64], a2 = wr[t + 128], a3 = wr[t + 192];
        float4 b0 = wz[t], b1 = wz[t + 64], b2 = wz[t + 128], b3 = wz[t + 192];
        float4 c0 = wn[t], c1 = wn[t + 64], c2 = wn[t + 128], c3 = wn[t + 192];

        // ih rows: 128 float4 each -> 2/lane (8 loads)
        float4 e0 = ev[t], e1 = ev[t + 64];
        float4 p0 = pr[t], p1 = pr[t + 64];
        float4 q0 = pz[t], q1 = pz[t + 64];
        float4 r0 = pn[t], r1 = pn[t + 64];

        float s_r = dot4(a0, x0) + dot4(a1, x1) + dot4(a2, x2) + dot4(a3, x3);
        float s_z = dot4(b0, x0) + dot4(b1, x1) + dot4(b2, x2) + dot4(b3, x3);
        float s_n = dot4(c0, x0) + dot4(c1, x1) + dot4(c2, x2) + dot4(c3, x3);

        // weight half 2 (regs reused)
        a0 = wr[t + 256]; a1 = wr[t + 320]; a2 = wr[t + 384]; a3 = wr[t + 448];
        b0 = wz[t + 256]; b1 = wz[t + 320]; b2 = wz[t + 384]; b3 = wz[t + 448];
        c0 = wn[t + 256]; c1 = wn[t + 320]; c2 = wn[t + 384]; c3 = wn[t + 448];

        float s_i = dot4(r0, e0) + dot4(r1, e1);          // i_n (kept separate)
        s_r += dot4(p0, e0) + dot4(p1, e1);               // i_r + h_r merged
        s_z += dot4(q0, e0) + dot4(q1, e1);               // i_z + h_z merged

        s_r += dot4(a0, x4) + dot4(a1, x5) + dot4(a2, x6) + dot4(a3, x7);
        s_z += dot4(b0, x4) + dot4(b1, x5) + dot4(b2, x6) + dot4(b3, x7);
        s_n += dot4(c0, x4) + dot4(c1, x5) + dot4(c2, x6) + dot4(c3, x7);

        s_r = wred(s_r); s_z = wred(s_z); s_n = wred(s_n); s_i = wred(s_i);
        if (t == 0) {
            float r  = sig(s_r + bi_r + bh_r);
            float z  = sig(s_z + bi_z + bh_z);
            float hn = s_n + bh_n;
            float n  = tanhf(s_i + bi_n + r * hn);
            out[NV + j] = (1.0f - z) * n + z * hprev;
        }
    } else {
        const int j = (bid - 512) * 4 + wv;
        const float bh_r = b_hh1[j];
        const float bh_z = b_hh1[j + HID];
        const float bh_n = b_hh1[j + 2 * HID];

        const float4* hv = (const float4*)(h_in + HID);               // h_in[1]
        const float4* wr = (const float4*)(w_hh1 + (size_t)j * HID);
        const float4* wz = (const float4*)(w_hh1 + (size_t)(j + HID) * HID);
        const float4* wn = (const float4*)(w_hh1 + (size_t)(j + 2 * HID) * HID);

        float4 x0 = hv[t],       x1 = hv[t + 64],  x2 = hv[t + 128], x3 = hv[t + 192];
        float4 x4 = hv[t + 256], x5 = hv[t + 320], x6 = hv[t + 384], x7 = hv[t + 448];

        float4 a0 = wr[t], a1 = wr[t + 64], a2 = wr[t + 128], a3 = wr[t + 192];
        float4 b0 = wz[t], b1 = wz[t + 64], b2 = wz[t + 128], b3 = wz[t + 192];
        float4 c0 = wn[t], c1 = wn[t + 64], c2 = wn[t + 128], c3 = wn[t + 192];

        float s_r = dot4(a0, x0) + dot4(a1, x1) + dot4(a2, x2) + dot4(a3, x3);
        float s_z = dot4(b0, x0) + dot4(b1, x1) + dot4(b2, x2) + dot4(b3, x3);
        float s_n = dot4(c0, x0) + dot4(c1, x1) + dot4(c2, x2) + dot4(c3, x3);

        a0 = wr[t + 256]; a1 = wr[t + 320]; a2 = wr[t + 384]; a3 = wr[t + 448];
        b0 = wz[t + 256]; b1 = wz[t + 320]; b2 = wz[t + 384]; b3 = wz[t + 448];
        c0 = wn[t + 256]; c1 = wn[t + 320]; c2 = wn[t + 384]; c3 = wn[t + 448];

        s_r += dot4(a0, x4) + dot4(a1, x5) + dot4(a2, x6) + dot4(a3, x7);
        s_z += dot4(b0, x4) + dot4(b1, x5) + dot4(b2, x6) + dot4(b3, x7);
        s_n += dot4(c0, x4) + dot4(c1, x5) + dot4(c2, x6) + dot4(c3, x7);

        s_r = wred(s_r); s_z = wred(s_z); s_n = wred(s_n);
        if (t == 0) {
            gh1[j]           = s_r + bh_r;
            gh1[j + HID]     = s_z + bh_z;
            gh1[j + 2 * HID] = s_n + bh_n;
        }
    }
}

// k2: one wave per h1 row, 4 rows/block, 512 blocks. No barriers.
__global__ __launch_bounds__(256, 4) void k2(
    const float* __restrict__ h_in,
    const float* __restrict__ w_ih1,
    const float* __restrict__ b_ih1,
    const float* __restrict__ gh1,
    float* __restrict__ out)
{
    const int tid = threadIdx.x;
    const int t   = tid & 63;
    const int wv  = tid >> 6;
    const int j   = blockIdx.x * 4 + wv;

    const float bi_r = b_ih1[j];
    const float bi_z = b_ih1[j + HID];
    const float bi_n = b_ih1[j + 2 * HID];
    const float g_r  = gh1[j];
    const float g_z  = gh1[j + HID];
    const float g_n  = gh1[j + 2 * HID];
    const float hprev = h_in[HID + j];

    const float4* hv = (const float4*)(out + NV);                     // h0 from k1
    const float4* wr = (const float4*)(w_ih1 + (size_t)j * HID);
    const float4* wz = (const float4*)(w_ih1 + (size_t)(j + HID) * HID);
    const float4* wn = (const float4*)(w_ih1 + (size_t)(j + 2 * HID) * HID);

    float4 x0 = hv[t],       x1 = hv[t + 64],  x2 = hv[t + 128], x3 = hv[t + 192];
    float4 x4 = hv[t + 256], x5 = hv[t + 320], x6 = hv[t + 384], x7 = hv[t + 448];

    float4 a0 = wr[t], a1 = wr[t + 64], a2 = wr[t + 128], a3 = wr[t + 192];
    float4 b0 = wz[t], b1 = wz[t + 64], b2 = wz[t + 128], b3 = wz[t + 192];
    float4 c0 = wn[t], c1 = wn[t + 64], c2 = wn[t + 128], c3 = wn[t + 192];

    float s_r = dot4(a0, x0) + dot4(a1, x1) + dot4(a2, x2) + dot4(a3, x3);
    float s_z = dot4(b0, x0) + dot4(b1, x1) + dot4(b2, x2) + dot4(b3, x3);
    float s_n = dot4(c0, x0) + dot4(c1, x1) + dot4(c2, x2) + dot4(c3, x3);

    a0 = wr[t + 256]; a1 = wr[t + 320]; a2 = wr[t + 384]; a3 = wr[t + 448];
    b0 = wz[t + 256]; b1 = wz[t + 320]; b2 = wz[t + 384]; b3 = wz[t + 448];
    c0 = wn[t + 256]; c1 = wn[t + 320]; c2 = wn[t + 384]; c3 = wn[t + 448];

    s_r += dot4(a0, x4) + dot4(a1, x5) + dot4(a2, x6) + dot4(a3, x7);
    s_z += dot4(b0, x4) + dot4(b1, x5) + dot4(b2, x6) + dot4(b3, x7);
    s_n += dot4(c0, x4) + dot4(c1, x5) + dot4(c2, x6) + dot4(c3, x7);

    s_r = wred(s_r); s_z = wred(s_z); s_n = wred(s_n);
    if (t == 0) {
        float r = sig(s_r + bi_r + g_r);
        float z = sig(s_z + bi_z + g_z);
        float n = tanhf(s_n + bi_n + r * g_n);
        out[NV + HID + j] = (1.0f - z) * n + z * hprev;
    }
}

// k3: logits = w_head @ h1 + b_head; softmax -> probs.
// 1024 threads: one wave per output row (16 rows), 8 chunks/lane.
__global__ __launch_bounds__(1024) void k3(
    const float* __restrict__ w_head,
    const float* __restrict__ b_head,
    float* __restrict__ out)
{
    const int tid  = threadIdx.x;
    const int row  = tid >> 6;   // 0..15
    const int lane = tid & 63;
    const float bh = b_head[row];
    const float4* hv = (const float4*)(out + NV + HID);               // h1 from k2
    const float4* w  = (const float4*)(w_head + (size_t)row * HID);

    float s = 0.f;
#pragma unroll
    for (int c = lane; c < HID / 4; c += 64) {
        s += dot4(w[c], hv[c]);
    }
    s = wred(s);

    __shared__ float logits[NV];
    if (lane == 0) logits[row] = s + bh;
    __syncthreads();
    if (tid == 0) {
        float m = logits[0];
#pragma unroll
        for (int i = 1; i < NV; ++i) m = fmaxf(m, logits[i]);
        float ex[NV]; float den = 0.f;
#pragma unroll
        for (int i = 0; i < NV; ++i) { ex[i] = __expf(logits[i] - m); den += ex[i]; }
        float inv = 1.0f / den;
#pragma unroll
        for (int i = 0; i < NV; ++i) out[i] = ex[i] * inv;
    }
}

extern "C" void kernel_launch(void* const* d_in, const int* in_sizes, int n_in,
                              void* d_out, int out_size, void* d_ws, size_t ws_size,
                              hipStream_t stream) {
    const int*   x      = (const int*)  d_in[0];
    const float* h_in   = (const float*)d_in[1];
    const float* emb    = (const float*)d_in[2];
    const float* w_ih0  = (const float*)d_in[3];
    const float* w_hh0  = (const float*)d_in[4];
    const float* b_ih0  = (const float*)d_in[5];
    const float* b_hh0  = (const float*)d_in[6];
    const float* w_ih1  = (const float*)d_in[7];
    const float* w_hh1  = (const float*)d_in[8];
    const float* b_ih1  = (const float*)d_in[9];
    const float* b_hh1  = (const float*)d_in[10];
    const float* w_head = (const float*)d_in[11];
    const float* b_head = (const float*)d_in[12];
    float* out = (float*)d_out;
    float* gh1 = (float*)d_ws;  // 6144 floats

    k1<<<1024, 256, 0, stream>>>(x, h_in, emb, w_ih0, w_hh0, b_ih0, b_hh0,
                                 w_hh1, b_hh1, out, gh1);
    k2<<<512, 256, 0, stream>>>(h_in, w_ih1, b_ih1, gh1, out);
    k3<<<1, 1024, 0, stream>>>(w_head, b_head, out);
}

// Round 8
// 34.347 us; speedup vs baseline: 1.0459x; 1.0459x over previous
//
#include <hip/hip_runtime.h>
#include <math.h>

#define HID 2048
#define EMB 512
#define NV 16

typedef float vfloat4 __attribute__((ext_vector_type(4)));

__device__ __forceinline__ float4 ntload4(const float4* p) {
    vfloat4 v = __builtin_nontemporal_load((const vfloat4*)p);
    return *(const float4*)&v;
}

__device__ __forceinline__ float wred(float v) {
#pragma unroll
    for (int o = 32; o >= 1; o >>= 1) v += __shfl_down(v, o, 64);
    return v;
}

__device__ __forceinline__ float dot4(float4 a, float4 b) {
    return a.x * b.x + a.y * b.y + a.z * b.z + a.w * b.w;
}

__device__ __forceinline__ float sig(float x) { return 1.0f / (1.0f + __expf(-x)); }

// k1: computes h0 (blocks 0..2047) and gh1 = w_hh1 @ h_in[1] + b_hh1 (blocks 2048..4095)
// R6 structure (best timed config). Weight streams use nontemporal loads: read-once
// data, no reuse -> skip L2/L3 allocation (avoids dirty-eviction writebacks).
__global__ __launch_bounds__(256, 4) void k1(
    const int* __restrict__ xidx,
    const float* __restrict__ h_in,
    const float* __restrict__ emb,
    const float* __restrict__ w_ih0,
    const float* __restrict__ w_hh0,
    const float* __restrict__ b_ih0,
    const float* __restrict__ b_hh0,
    const float* __restrict__ w_hh1,
    const float* __restrict__ b_hh1,
    float* __restrict__ out,
    float* __restrict__ gh1)
{
    const int tid  = threadIdx.x;
    const int lane = tid & 63;
    const int wv   = tid >> 6;
    const int bid  = blockIdx.x;
    __shared__ float red[4][6];

    float s0 = 0.f, s1 = 0.f, s2 = 0.f, s3 = 0.f, s4 = 0.f, s5 = 0.f;

    if (bid < HID) {
        const int j = bid;
        const float4* wh0 = (const float4*)(w_hh0 + (size_t)j * HID);
        const float4* wh1 = (const float4*)(w_hh0 + (size_t)(j + HID) * HID);
        const float4* wh2 = (const float4*)(w_hh0 + (size_t)(j + 2 * HID) * HID);
        const float4* hv  = (const float4*)h_in;                      // h_in[0]

        // weight streams first (HBM-critical, nontemporal), then x (cached)
        float4 a0 = ntload4(&wh0[tid]);
        float4 a1 = ntload4(&wh0[tid + 256]);
        float4 b0 = ntload4(&wh1[tid]);
        float4 b1 = ntload4(&wh1[tid + 256]);
        float4 d0 = ntload4(&wh2[tid]);
        float4 d1 = ntload4(&wh2[tid + 256]);
        float4 x0 = hv[tid];
        float4 x1 = hv[tid + 256];

        // epilogue scalars (broadcast loads)
        const float bi_r = b_ih0[j];
        const float bi_z = b_ih0[j + HID];
        const float bi_n = b_ih0[j + 2 * HID];
        const float bh_r = b_hh0[j];
        const float bh_z = b_hh0[j + HID];
        const float bh_n = b_hh0[j + 2 * HID];
        const float hprev = h_in[j];

        if (tid < 128) {
            const float4* wi0 = (const float4*)(w_ih0 + (size_t)j * EMB);
            const float4* wi1 = (const float4*)(w_ih0 + (size_t)(j + HID) * EMB);
            const float4* wi2 = (const float4*)(w_ih0 + (size_t)(j + 2 * HID) * EMB);
            const float4* ev  = (const float4*)(emb + (size_t)xidx[0] * EMB);
            float4 ia = ntload4(&wi0[tid]);
            float4 ib = ntload4(&wi1[tid]);
            float4 ic = ntload4(&wi2[tid]);
            float4 e4 = ev[tid];
            s0 = dot4(ia, e4);
            s1 = dot4(ib, e4);
            s2 = dot4(ic, e4);
        }

        s3 = dot4(a0, x0) + dot4(a1, x1);
        s4 = dot4(b0, x0) + dot4(b1, x1);
        s5 = dot4(d0, x0) + dot4(d1, x1);

        s0 = wred(s0); s1 = wred(s1); s2 = wred(s2);
        s3 = wred(s3); s4 = wred(s4); s5 = wred(s5);
        if (lane == 0) {
            red[wv][0] = s0; red[wv][1] = s1; red[wv][2] = s2;
            red[wv][3] = s3; red[wv][4] = s4; red[wv][5] = s5;
        }
        __syncthreads();
        if (tid == 0) {
            float ir  = red[0][0] + red[1][0] + red[2][0] + red[3][0] + bi_r;
            float iz  = red[0][1] + red[1][1] + red[2][1] + red[3][1] + bi_z;
            float inn = red[0][2] + red[1][2] + red[2][2] + red[3][2] + bi_n;
            float hr  = red[0][3] + red[1][3] + red[2][3] + red[3][3] + bh_r;
            float hz  = red[0][4] + red[1][4] + red[2][4] + red[3][4] + bh_z;
            float hn  = red[0][5] + red[1][5] + red[2][5] + red[3][5] + bh_n;
            float r = sig(ir + hr);
            float z = sig(iz + hz);
            float n = tanhf(inn + r * hn);
            out[NV + j] = (1.0f - z) * n + z * hprev;
        }
    } else {
        const int j = bid - HID;
        const float4* wh0 = (const float4*)(w_hh1 + (size_t)j * HID);
        const float4* wh1 = (const float4*)(w_hh1 + (size_t)(j + HID) * HID);
        const float4* wh2 = (const float4*)(w_hh1 + (size_t)(j + 2 * HID) * HID);
        const float4* hv  = (const float4*)(h_in + HID);              // h_in[1]

        float4 a0 = ntload4(&wh0[tid]);
        float4 a1 = ntload4(&wh0[tid + 256]);
        float4 b0 = ntload4(&wh1[tid]);
        float4 b1 = ntload4(&wh1[tid + 256]);
        float4 d0 = ntload4(&wh2[tid]);
        float4 d1 = ntload4(&wh2[tid + 256]);
        float4 x0 = hv[tid];
        float4 x1 = hv[tid + 256];

        const float bh_r = b_hh1[j];
        const float bh_z = b_hh1[j + HID];
        const float bh_n = b_hh1[j + 2 * HID];

        s0 = dot4(a0, x0) + dot4(a1, x1);
        s1 = dot4(b0, x0) + dot4(b1, x1);
        s2 = dot4(d0, x0) + dot4(d1, x1);

        s0 = wred(s0); s1 = wred(s1); s2 = wred(s2);
        if (lane == 0) {
            red[wv][0] = s0; red[wv][1] = s1; red[wv][2] = s2;
        }
        __syncthreads();
        if (tid == 0) {
            gh1[j]           = red[0][0] + red[1][0] + red[2][0] + red[3][0] + bh_r;
            gh1[j + HID]     = red[0][1] + red[1][1] + red[2][1] + red[3][1] + bh_z;
            gh1[j + 2 * HID] = red[0][2] + red[1][2] + red[2][2] + red[3][2] + bh_n;
        }
    }
}

// k2: gi1 = w_ih1 @ h0 + b_ih1; combine with gh1 -> h1
__global__ __launch_bounds__(256, 4) void k2(
    const float* __restrict__ h_in,
    const float* __restrict__ w_ih1,
    const float* __restrict__ b_ih1,
    const float* __restrict__ gh1,
    float* __restrict__ out)
{
    const int tid  = threadIdx.x;
    const int lane = tid & 63;
    const int wv   = tid >> 6;
    const int j    = blockIdx.x;
    __shared__ float red[4][3];

    const float4* wi0 = (const float4*)(w_ih1 + (size_t)j * HID);
    const float4* wi1 = (const float4*)(w_ih1 + (size_t)(j + HID) * HID);
    const float4* wi2 = (const float4*)(w_ih1 + (size_t)(j + 2 * HID) * HID);
    const float4* hv  = (const float4*)(out + NV);                    // h0 from k1

    float4 a0 = ntload4(&wi0[tid]);
    float4 a1 = ntload4(&wi0[tid + 256]);
    float4 b0 = ntload4(&wi1[tid]);
    float4 b1 = ntload4(&wi1[tid + 256]);
    float4 d0 = ntload4(&wi2[tid]);
    float4 d1 = ntload4(&wi2[tid + 256]);
    float4 x0 = hv[tid];
    float4 x1 = hv[tid + 256];

    const float bi_r = b_ih1[j];
    const float bi_z = b_ih1[j + HID];
    const float bi_n = b_ih1[j + 2 * HID];
    const float g_r  = gh1[j];
    const float g_z  = gh1[j + HID];
    const float g_n  = gh1[j + 2 * HID];
    const float hprev = h_in[HID + j];

    float s0 = dot4(a0, x0) + dot4(a1, x1);
    float s1 = dot4(b0, x0) + dot4(b1, x1);
    float s2 = dot4(d0, x0) + dot4(d1, x1);

    s0 = wred(s0); s1 = wred(s1); s2 = wred(s2);
    if (lane == 0) { red[wv][0] = s0; red[wv][1] = s1; red[wv][2] = s2; }
    __syncthreads();
    if (tid == 0) {
        float ir  = red[0][0] + red[1][0] + red[2][0] + red[3][0] + bi_r;
        float iz  = red[0][1] + red[1][1] + red[2][1] + red[3][1] + bi_z;
        float inn = red[0][2] + red[1][2] + red[2][2] + red[3][2] + bi_n;
        float r = sig(ir + g_r);
        float z = sig(iz + g_z);
        float n = tanhf(inn + r * g_n);
        out[NV + HID + j] = (1.0f - z) * n + z * hprev;
    }
}

// k3: logits = w_head @ h1 + b_head; softmax -> probs.
// 1024 threads: one wave per output row (16 rows), 8 chunks/lane.
__global__ __launch_bounds__(1024) void k3(
    const float* __restrict__ w_head,
    const float* __restrict__ b_head,
    float* __restrict__ out)
{
    const int tid  = threadIdx.x;
    const int row  = tid >> 6;   // 0..15
    const int lane = tid & 63;
    const float bh = b_head[row];
    const float4* hv = (const float4*)(out + NV + HID);               // h1 from k2
    const float4* w  = (const float4*)(w_head + (size_t)row * HID);

    float s = 0.f;
#pragma unroll
    for (int c = lane; c < HID / 4; c += 64) {
        s += dot4(w[c], hv[c]);
    }
    s = wred(s);

    __shared__ float logits[NV];
    if (lane == 0) logits[row] = s + bh;
    __syncthreads();
    if (tid == 0) {
        float m = logits[0];
#pragma unroll
        for (int i = 1; i < NV; ++i) m = fmaxf(m, logits[i]);
        float ex[NV]; float den = 0.f;
#pragma unroll
        for (int i = 0; i < NV; ++i) { ex[i] = __expf(logits[i] - m); den += ex[i]; }
        float inv = 1.0f / den;
#pragma unroll
        for (int i = 0; i < NV; ++i) out[i] = ex[i] * inv;
    }
}

extern "C" void kernel_launch(void* const* d_in, const int* in_sizes, int n_in,
                              void* d_out, int out_size, void* d_ws, size_t ws_size,
                              hipStream_t stream) {
    const int*   x      = (const int*)  d_in[0];
    const float* h_in   = (const float*)d_in[1];
    const float* emb    = (const float*)d_in[2];
    const float* w_ih0  = (const float*)d_in[3];
    const float* w_hh0  = (const float*)d_in[4];
    const float* b_ih0  = (const float*)d_in[5];
    const float* b_hh0  = (const float*)d_in[6];
    const float* w_ih1  = (const float*)d_in[7];
    const float* w_hh1  = (const float*)d_in[8];
    const float* b_ih1  = (const float*)d_in[9];
    const float* b_hh1  = (const float*)d_in[10];
    const float* w_head = (const float*)d_in[11];
    const float* b_head = (const float*)d_in[12];
    float* out = (float*)d_out;
    float* gh1 = (float*)d_ws;  // 6144 floats

    k1<<<2 * HID, 256, 0, stream>>>(x, h_in, emb, w_ih0, w_hh0, b_ih0, b_hh0,
                                    w_hh1, b_hh1, out, gh1);
    k2<<<HID, 256, 0, stream>>>(h_in, w_ih1, b_ih1, gh1, out);
    k3<<<1, 1024, 0, stream>>>(w_head, b_head, out);
}